// Round 4
// baseline (509.086 us; speedup 1.0000x reference)
//
#include <hip/hip_runtime.h>
#include <stdint.h>

typedef __fp16 f16x2 __attribute__((ext_vector_type(2)));
typedef __fp16 f16x8 __attribute__((ext_vector_type(8)));
typedef float  f32x4 __attribute__((ext_vector_type(4)));

#define GLOBAL_AS __attribute__((address_space(1)))
#define LDS_AS    __attribute__((address_space(3)))

#define NN   8192
#define INC  256
#define OUTC 256
#define K2   2048                    // INC * RR
#define YTN  ((size_t)OUTC * NN)     // 2M elements

// counted waits (T4): NEVER drain vmcnt to 0 in the main loop
#define WAIT_VMCNT_6() asm volatile("s_waitcnt vmcnt(6)" ::: "memory")
#define WAIT_VMCNT_0() asm volatile("s_waitcnt vmcnt(0)" ::: "memory")

__device__ __forceinline__ void async_copy16(const void* g, void* l) {
    // 16B per lane; LDS dest = wave-uniform base + lane*16 (m97/m104 semantics)
    __builtin_amdgcn_global_load_lds((const GLOBAL_AS uint32_t*)g,
                                     (LDS_AS uint32_t*)l, 16, 0, 0);
}

__device__ __forceinline__ f16x8 cvt_f32x8_to_f16x8(f32x4 u0, f32x4 u1) {
    f16x8 out;
    f16x2* p = (f16x2*)&out;
    p[0] = __builtin_amdgcn_cvt_pkrtz(u0[0], u0[1]);
    p[1] = __builtin_amdgcn_cvt_pkrtz(u0[2], u0[3]);
    p[2] = __builtin_amdgcn_cvt_pkrtz(u1[0], u1[1]);
    p[3] = __builtin_amdgcn_cvt_pkrtz(u1[2], u1[3]);
    return out;
}

// ---------------------------------------------------------------------------
// W2T16[o][k] = sum_b w_rel[r,b] * w_bases[b,i,o],  k = i*8+r, f16 output.
// ---------------------------------------------------------------------------
__global__ void build_w2t16(const float* __restrict__ wb, const float* __restrict__ wr,
                            __fp16* __restrict__ W2T16) {
    int o = blockIdx.x;      // 0..255
    int i = threadIdx.x;     // 0..255
    float s[8];
#pragma unroll
    for (int r = 0; r < 8; ++r) s[r] = 0.f;
#pragma unroll
    for (int b = 0; b < 4; ++b) {
        float w = wb[((size_t)((b << 8) + i)) * OUTC + o];
#pragma unroll
        for (int r = 0; r < 8; ++r) s[r] = fmaf(wr[r * 4 + b], w, s[r]);
    }
    f16x8 out;
    f16x2* p = (f16x2*)&out;
    p[0] = __builtin_amdgcn_cvt_pkrtz(s[0], s[1]);
    p[1] = __builtin_amdgcn_cvt_pkrtz(s[2], s[3]);
    p[2] = __builtin_amdgcn_cvt_pkrtz(s[4], s[5]);
    p[3] = __builtin_amdgcn_cvt_pkrtz(s[6], s[7]);
    *reinterpret_cast<f16x8*>(&W2T16[(size_t)o * K2 + i * 8]) = out;
}

// ---------------------------------------------------------------------------
// GEMM1: yT_p[z][o][m] = W2T16[o][:] . x[m][:]   (M=256 o, N=8192 m, K=2048)
//   A = W2T16 f16 [256][2048]  -> LDS 3-deep, XOR-swizzle ((r>>1)&3), 16B chunks
//   B = x      f32 [8192][2048] -> LDS 3-deep (as f32), XOR-swizzle (r&7), cvt@read
// Tile 128x128x32, 4 waves (2x2), wave 64x64, acc[4][4].
// Schedule per iter: vmcnt(6) [tile t landed, t+1 in flight] -> s_barrier ->
// stage(t+2) -> compute(t). 3 buffers x 24KB = 72KB -> 2 blocks/CU.
// Per wave per tile: 2 (A) + 4 (B) = 6 global_load_lds  => vmcnt(6).
// ---------------------------------------------------------------------------
__global__ __launch_bounds__(256, 2)
void gemm1_p3(const __fp16* __restrict__ W2, const float* __restrict__ X,
              float* __restrict__ Cp, int kPerSplit) {
    __shared__ __align__(16) __fp16 As[3][128 * 32];   //  8KB x3
    __shared__ __align__(16) float  Bs[3][128 * 32];   // 16KB x3

    const int bm = blockIdx.x * 128;   // o
    const int bn = blockIdx.y * 128;   // m
    const int k0 = blockIdx.z * kPerSplit;

    const int tid  = threadIdx.x;
    const int lane = tid & 63;
    const int wave = tid >> 6;
    const int wm   = (wave >> 1) * 64;
    const int wn   = (wave & 1) * 64;
    const int quad = lane >> 4;
    const int l16  = lane & 15;

    f32x4 acc[4][4];
#pragma unroll
    for (int ti = 0; ti < 4; ++ti)
#pragma unroll
        for (int tj = 0; tj < 4; ++tj)
            acc[ti][tj] = (f32x4){0.f, 0.f, 0.f, 0.f};

    const int nt = kPerSplit / 32;

    auto stage = [&](int buf, int kc) {
        // A: 128 rows x 32 f16 (2 instrs/wave, 16 rows each)
#pragma unroll
        for (int i = 0; i < 2; ++i) {
            int r0 = wave * 32 + i * 16;
            int r  = r0 + (lane >> 2);
            int c  = (lane & 3) ^ ((r >> 1) & 3);
            async_copy16(W2 + (size_t)(bm + r) * K2 + kc + c * 8,
                         (char*)As[buf] + r0 * 64);
        }
        // B: 128 rows x 32 f32 (4 instrs/wave, 8 rows each)
#pragma unroll
        for (int i = 0; i < 4; ++i) {
            int r0 = wave * 32 + i * 8;
            int r  = r0 + (lane >> 3);
            int c  = (lane & 7) ^ (r & 7);
            async_copy16(X + (size_t)(bn + r) * K2 + kc + (c << 2),
                         (char*)Bs[buf] + r0 * 128);
        }
    };

    auto compute = [&](int buf) {
        f16x8 af[4];
#pragma unroll
        for (int j = 0; j < 4; ++j) {
            int row = wm + j * 16 + l16;
            int p   = quad ^ ((row >> 1) & 3);
            af[j] = *(const f16x8*)(&As[buf][0] + row * 32 + p * 8);
        }
        f16x8 bf[4];
#pragma unroll
        for (int j = 0; j < 4; ++j) {
            int row = wn + j * 16 + l16;
            int p0  = (2 * quad)     ^ (row & 7);
            int p1  = (2 * quad + 1) ^ (row & 7);
            f32x4 u0 = *(const f32x4*)(&Bs[buf][0] + row * 32 + p0 * 4);
            f32x4 u1 = *(const f32x4*)(&Bs[buf][0] + row * 32 + p1 * 4);
            bf[j] = cvt_f32x8_to_f16x8(u0, u1);
        }
#pragma unroll
        for (int ti = 0; ti < 4; ++ti)
#pragma unroll
            for (int tj = 0; tj < 4; ++tj)
                acc[ti][tj] = __builtin_amdgcn_mfma_f32_16x16x32_f16(
                    af[ti], bf[tj], acc[ti][tj], 0, 0, 0);
    };

    stage(0, k0);
    stage(1, k0 + 32);

    int t = 0;
    for (; t < nt - 1; ++t) {
        WAIT_VMCNT_6();                      // tile t fully landed (mine)
        __builtin_amdgcn_s_barrier();        // everyone's tile t landed
        if (t + 2 < nt) stage((t + 2) % 3, k0 + (t + 2) * 32);
        compute(t % 3);
    }
    WAIT_VMCNT_0();
    __builtin_amdgcn_s_barrier();
    compute((nt - 1) % 3);

    float* Cz = Cp + (size_t)blockIdx.z * 256 * NN;
#pragma unroll
    for (int ti = 0; ti < 4; ++ti)
#pragma unroll
        for (int tj = 0; tj < 4; ++tj)
#pragma unroll
            for (int r = 0; r < 4; ++r) {
                int row = bm + wm + ti * 16 + quad * 4 + r;   // o
                int col = bn + wn + tj * 16 + l16;            // m
                Cz[(size_t)row * NN + col] = acc[ti][tj][r];
            }
}

// ---------------------------------------------------------------------------
// GEMM2: out_p[z][n][o] = a[n][:] . yT16[o][:]   (M=8192 n, N=256 o, K=8192)
//   A = a    f32 [8192][8192] -> LDS 3-deep (as f32), XOR-swizzle (r&7), cvt@read
//   B = yT16 f16 [256][8192]  -> LDS 3-deep, XOR-swizzle ((r>>1)&3), full N
// Tile 64x256x32, 4 waves (2x2), wave 32x128, acc[2][8]. Same schedule.
// 3 buffers x 24KB = 72KB -> 2 blocks/CU. grid 128 x 1 x 8 = 1024 blocks.
// Per wave per tile: 2 (A) + 4 (B) = 6 global_load_lds  => vmcnt(6).
// a-traffic unchanged vs BM=128 (each row still fetched exactly once).
// ---------------------------------------------------------------------------
__global__ __launch_bounds__(256, 2)
void gemm2_p3(const float* __restrict__ A, const __fp16* __restrict__ Y,
              float* __restrict__ Cp, int kPerSplit) {
    __shared__ __align__(16) float  As[3][64 * 32];    //  8KB x3
    __shared__ __align__(16) __fp16 Bs[3][256 * 32];   // 16KB x3

    const int bm = blockIdx.x * 64;    // n
    const int k0 = blockIdx.z * kPerSplit;

    const int tid  = threadIdx.x;
    const int lane = tid & 63;
    const int wave = tid >> 6;
    const int wm   = (wave >> 1) * 32;    // 0 / 32
    const int wn   = (wave & 1) * 128;    // 0 / 128
    const int quad = lane >> 4;
    const int l16  = lane & 15;

    f32x4 acc[2][8];
#pragma unroll
    for (int ti = 0; ti < 2; ++ti)
#pragma unroll
        for (int tj = 0; tj < 8; ++tj)
            acc[ti][tj] = (f32x4){0.f, 0.f, 0.f, 0.f};

    const int nt = kPerSplit / 32;

    auto stage = [&](int buf, int kc) {
        // A: 64 rows x 32 f32 (2 instrs/wave, 8 rows each)
#pragma unroll
        for (int i = 0; i < 2; ++i) {
            int r0 = wave * 16 + i * 8;
            int r  = r0 + (lane >> 3);
            int c  = (lane & 7) ^ (r & 7);
            async_copy16(A + (size_t)(bm + r) * NN + kc + (c << 2),
                         (char*)As[buf] + r0 * 128);
        }
        // B: 256 rows x 32 f16 (4 instrs/wave, 16 rows each)
#pragma unroll
        for (int i = 0; i < 4; ++i) {
            int r0 = wave * 64 + i * 16;
            int r  = r0 + (lane >> 2);
            int c  = (lane & 3) ^ ((r >> 1) & 3);
            async_copy16(Y + (size_t)r * NN + kc + c * 8,
                         (char*)Bs[buf] + r0 * 64);
        }
    };

    auto compute = [&](int buf) {
        f16x8 af[2];
#pragma unroll
        for (int j = 0; j < 2; ++j) {
            int row = wm + j * 16 + l16;
            int p0  = (2 * quad)     ^ (row & 7);
            int p1  = (2 * quad + 1) ^ (row & 7);
            f32x4 u0 = *(const f32x4*)(&As[buf][0] + row * 32 + p0 * 4);
            f32x4 u1 = *(const f32x4*)(&As[buf][0] + row * 32 + p1 * 4);
            af[j] = cvt_f32x8_to_f16x8(u0, u1);
        }
        f16x8 bf[8];
#pragma unroll
        for (int j = 0; j < 8; ++j) {
            int row = wn + j * 16 + l16;
            int p   = quad ^ ((row >> 1) & 3);
            bf[j] = *(const f16x8*)(&Bs[buf][0] + row * 32 + p * 8);
        }
#pragma unroll
        for (int ti = 0; ti < 2; ++ti)
#pragma unroll
            for (int tj = 0; tj < 8; ++tj)
                acc[ti][tj] = __builtin_amdgcn_mfma_f32_16x16x32_f16(
                    af[ti], bf[tj], acc[ti][tj], 0, 0, 0);
    };

    stage(0, k0);
    stage(1, k0 + 32);

    int t = 0;
    for (; t < nt - 1; ++t) {
        WAIT_VMCNT_6();
        __builtin_amdgcn_s_barrier();
        if (t + 2 < nt) stage((t + 2) % 3, k0 + (t + 2) * 32);
        compute(t % 3);
    }
    WAIT_VMCNT_0();
    __builtin_amdgcn_s_barrier();
    compute((nt - 1) % 3);

    float* Cz = Cp + (size_t)blockIdx.z * NN * 256;
#pragma unroll
    for (int ti = 0; ti < 2; ++ti)
#pragma unroll
        for (int tj = 0; tj < 8; ++tj)
#pragma unroll
            for (int r = 0; r < 4; ++r) {
                int row = bm + wm + ti * 16 + quad * 4 + r;   // n
                int col = wn + tj * 16 + l16;                 // o
                Cz[(size_t)row * 256 + col] = acc[ti][tj][r];
            }
}

// ---------------------------------------------------------------------------
// yT16[i] = (f16) sum_{z<4} yT_p[z][i]
// ---------------------------------------------------------------------------
__global__ void reduce_yT(const float* __restrict__ yTp, __fp16* __restrict__ yT16) {
    size_t base = ((size_t)blockIdx.x * 256 + threadIdx.x) * 8;
    f32x4 s0 = (f32x4){0.f, 0.f, 0.f, 0.f};
    f32x4 s1 = (f32x4){0.f, 0.f, 0.f, 0.f};
#pragma unroll
    for (int z = 0; z < 4; ++z) {
        const float* p = yTp + (size_t)z * YTN + base;
        s0 += *(const f32x4*)p;
        s1 += *(const f32x4*)(p + 4);
    }
    *reinterpret_cast<f16x8*>(&yT16[base]) = cvt_f32x8_to_f16x8(s0, s1);
}

// ---------------------------------------------------------------------------
// out[i] = sum_{z<8} out_p[z][i]
// ---------------------------------------------------------------------------
__global__ void reduce_out(const float* __restrict__ op, float* __restrict__ out) {
    size_t base = ((size_t)blockIdx.x * 256 + threadIdx.x) * 4;
    f32x4 s = (f32x4){0.f, 0.f, 0.f, 0.f};
#pragma unroll
    for (int z = 0; z < 8; ++z)
        s += *(const f32x4*)(op + (size_t)z * YTN + base);
    *reinterpret_cast<f32x4*>(&out[base]) = s;
}

// ---------------------------------------------------------------------------
extern "C" void kernel_launch(void* const* d_in, const int* in_sizes, int n_in,
                              void* d_out, int out_size, void* d_ws, size_t ws_size,
                              hipStream_t stream) {
    const float* a  = (const float*)d_in[0];   // [8192][8192]
    const float* x  = (const float*)d_in[1];   // [8192][2048] (k = i*8+r contiguous)
    const float* wb = (const float*)d_in[2];   // [4][256][256]
    const float* wr = (const float*)d_in[3];   // [8][4]
    float* out = (float*)d_out;                // [8192][256]

    // ws layout (101 MB total):
    //   [0,   32MB)  yT_p   : 4 x [256][8192] fp32 partials
    //   [32,  36MB)  yT16   : [256][8192] f16
    //   [36, 100MB)  out_p  : 8 x [8192][256] fp32 partials
    //   [100,101MB)  W2T16  : [256][2048] f16
    char* w = (char*)d_ws;
    float*  yT_p  = (float*)(w);
    __fp16* yT16  = (__fp16*)(w + ((size_t)32 << 20));
    float*  out_p = (float*)(w + ((size_t)36 << 20));
    __fp16* W2T16 = (__fp16*)(w + ((size_t)100 << 20));

    // 1) basis-combined weights, f16, [o][k]
    build_w2t16<<<dim3(256), dim3(256), 0, stream>>>(wb, wr, W2T16);

    // 2) yT_p[z][o][m] = W2T16[o][:] . x[m][:]   M=256,N=8192,K=2048, split 4
    gemm1_p3<<<dim3(2, 64, 4), dim3(256), 0, stream>>>(W2T16, x, yT_p, 512);

    // 3) yT16 = f16(sum_z yT_p)
    reduce_yT<<<dim3(1024), dim3(256), 0, stream>>>(yT_p, yT16);

    // 4) out_p[z][n][o] = a[n][:] . yT16[o][:]   M=8192,N=256(full),K=8192, split 8
    gemm2_p3<<<dim3(128, 1, 8), dim3(256), 0, stream>>>(a, yT16, out_p, 1024);

    // 5) out = sum_z out_p
    reduce_out<<<dim3(2048), dim3(256), 0, stream>>>(out_p, out);
}